// Round 14
// baseline (252.882 us; speedup 1.0000x reference)
//
#include <hip/hip_runtime.h>

typedef __attribute__((ext_vector_type(8))) _Float16 half8;
typedef __attribute__((ext_vector_type(2))) _Float16 half2v;
typedef __attribute__((ext_vector_type(4))) float f32x4;

#define NB 196       // dst buckets per relation (bucket width 256 nodes)
#define CHK 2048     // edges per bin/bhist block
#define CAPB 4096    // max raw edges per bucket (mean ~2551)
#define PSTRIDE 6144 // padded slots per bucket

// ---------- helpers ----------
__device__ __forceinline__ unsigned short f2h(float f) {
  _Float16 h = (_Float16)f;
  return __builtin_bit_cast(unsigned short, h);
}
__device__ __forceinline__ float fdot2(unsigned a, unsigned b, float c) {
  return __builtin_amdgcn_fdot2(__builtin_bit_cast(half2v, a), __builtin_bit_cast(half2v, b), c,
                                false);
}

#define DPPADD(v, ctrl) \
  ((v) + __int_as_float(__builtin_amdgcn_update_dpp(0, __float_as_int(v), ctrl, 0xF, 0xF, true)))

// ---------- fp32 -> f16 bulk convert (2 arrays) + zero-row init ----------
__global__ void cvt2_kernel(const float* __restrict__ a, unsigned short* __restrict__ oa,
                            const float* __restrict__ b, unsigned short* __restrict__ ob,
                            int n8, unsigned short* __restrict__ z0,
                            unsigned short* __restrict__ z1, unsigned short* __restrict__ z2) {
  int t = threadIdx.x;
  if (blockIdx.y == 2) {
    if (blockIdx.x == 0 && t < 192) {
      int r = t >> 6;
      unsigned short* z = r == 0 ? z0 : (r == 1 ? z1 : z2);
      ((uint2*)z)[t & 63] = make_uint2(0, 0);
    }
    return;
  }
  int i = blockIdx.x * 256 + t;
  if (i >= n8) return;
  const float* in = blockIdx.y ? b : a;
  unsigned short* out = blockIdx.y ? ob : oa;
  const float4* p = (const float4*)(in + (size_t)i * 8);
  float4 x = p[0], y = p[1];
  uint4 v;
  v.x = f2h(x.x) | ((unsigned)f2h(x.y) << 16);
  v.y = f2h(x.z) | ((unsigned)f2h(x.w) << 16);
  v.z = f2h(y.x) | ((unsigned)f2h(y.y) << 16);
  v.w = f2h(y.z) | ((unsigned)f2h(y.w) << 16);
  *(uint4*)(out + (size_t)i * 8) = v;
}

// ---------- composed relation weights (f16 out, fp32 bias) ----------
__global__ void compose_w_kernel(const float* __restrict__ Wk, const float* __restrict__ bk,
                                 const float* __restrict__ Wv, const float* __restrict__ bv,
                                 const float* __restrict__ rel_att, const float* __restrict__ rel_msg,
                                 const float* __restrict__ rel_pri,
                                 unsigned short* __restrict__ Wkr, float* __restrict__ bkr,
                                 unsigned short* __restrict__ Wvr, float* __restrict__ bvr) {
  int e = blockIdx.x;
  int o = blockIdx.y;
  int z = blockIdx.z;
  int c = threadIdx.x;
  int hd = o >> 4, j = o & 15;
  const int se[3] = {0, 1, 0};
  int s = se[e];
  const float* W = z ? Wv : Wk;
  const float* b = z ? bv : bk;
  const float* R = z ? rel_msg : rel_att;
  float scale = z ? 1.0f : (rel_pri[e * 8 + hd] * 0.25f);
  float acc = 0.0f, bacc = 0.0f;
#pragma unroll
  for (int i = 0; i < 16; ++i) {
    float r = R[((e * 8 + hd) * 16 + i) * 16 + j];
    acc += W[(s * 128 + hd * 16 + i) * 128 + c] * r;
    bacc += b[s * 128 + hd * 16 + i] * r;
  }
  unsigned short* Wo = z ? Wvr : Wkr;
  float* bo = z ? bvr : bkr;
  Wo[((size_t)e * 128 + o) * 128 + c] = f2h(acc * scale);
  if (c == 0) bo[e * 128 + o] = bacc * scale;
}

// ---------- fused MFMA projection GEMM (f16, B direct from global) ----------
struct ProjFP {
  const float* A[2];
  int M[2];
  int nj[2];
  const unsigned short* W[10];
  const float* b[10];
  unsigned short* out[10];
  int ostr[10];
};

__global__ __launch_bounds__(256) void proj_gemm_fused(ProjFP P) {
  __shared__ short As[128 * 128];
  int type = blockIdx.y;
  const float* __restrict__ A = P.A[type];
  int M = P.M[type];
  int nj = P.nj[type];
  int base = type * 5;
  int row0 = blockIdx.x * 128;
  if (row0 >= M) return;
  int t = threadIdx.x;
  bool full = (row0 + 128 <= M);
#pragma unroll
  for (int it = 0; it < 8; ++it) {
    int o = (it * 256 + t) * 8;
    int row = o >> 7, col = o & 127;
    int gr = row0 + row;
    uint4 av = make_uint4(0, 0, 0, 0);
    if (full || gr < M) {
      float4 x = *(const float4*)(A + (size_t)gr * 128 + col);
      float4 y = *(const float4*)(A + (size_t)gr * 128 + col + 4);
      av.x = f2h(x.x) | ((unsigned)f2h(x.y) << 16);
      av.y = f2h(x.z) | ((unsigned)f2h(x.w) << 16);
      av.z = f2h(y.x) | ((unsigned)f2h(y.y) << 16);
      av.w = f2h(y.z) | ((unsigned)f2h(y.w) << 16);
    }
    int sw = o ^ ((row & 7) << 3);
    *(uint4*)(&As[sw]) = av;
  }
  __syncthreads();
  int wid = t >> 6, l = t & 63;
  int wr = wid >> 1, wc = wid & 1;
  int lr = l & 15, kb = l >> 4;
  for (int j = 0;; ++j) {
    const unsigned short* __restrict__ W = P.W[base + j];
    f32x4 acc[4][4] = {};
#pragma unroll
    for (int ks = 0; ks < 4; ++ks) {
      half8 af[4], bfr[4];
#pragma unroll
      for (int m = 0; m < 4; ++m) {
        int row = wr * 64 + m * 16 + lr;
        int h = (row * 128 + kb * 8 + ks * 32) ^ ((row & 7) << 3);
        af[m] = *(half8*)(&As[h]);
      }
#pragma unroll
      for (int n = 0; n < 4; ++n) {
        int row = wc * 64 + n * 16 + lr;
        bfr[n] = *(const half8*)(W + (size_t)row * 128 + kb * 8 + ks * 32);
      }
#pragma unroll
      for (int m = 0; m < 4; ++m)
#pragma unroll
        for (int n = 0; n < 4; ++n)
          acc[m][n] = __builtin_amdgcn_mfma_f32_16x16x32_f16(af[m], bfr[n], acc[m][n], 0, 0, 0);
    }
    const float* bias = P.b[base + j];
    unsigned short* out = P.out[base + j];
    int ostr = P.ostr[base + j];
    int rb = row0 + wr * 64 + (l >> 4) * 4;
#pragma unroll
    for (int m = 0; m < 4; ++m)
#pragma unroll
      for (int jr = 0; jr < 4; ++jr) {
        int grow = rb + m * 16 + jr;
        if (grow < M) {
#pragma unroll
          for (int n = 0; n < 4; ++n) {
            int col = wc * 64 + n * 16 + lr;
            out[(size_t)grow * ostr + col] = f2h(acc[m][n][jr] + bias[col]);
          }
        }
      }
    if (j + 1 >= nj) break;
  }
}

// ---------- MFMA final GEMM (f16 inputs, fp32 out; B direct from global) ----------
__global__ __launch_bounds__(256) void final_gemm_mfma(
    float* __restrict__ dout, const unsigned short* __restrict__ Tb0,
    const unsigned short* __restrict__ Tb1, const unsigned short* __restrict__ Wab,
    const float* __restrict__ ba, const float* __restrict__ h0, const float* __restrict__ h1,
    const float* __restrict__ skip, int N0, int N1) {
  __shared__ short As[128 * 128];
  int type = blockIdx.y;
  int M = type ? N1 : N0;
  const unsigned short* T = type ? Tb1 : Tb0;
  const unsigned short* W = Wab + (size_t)type * 16384;
  const float* bias = ba + type * 128;
  const float* h = type ? h1 : h0;
  float* O = dout + (type ? (size_t)N0 * 128 : 0);
  int row0 = blockIdx.x * 128;
  if (row0 >= M) return;
  int t = threadIdx.x;
  bool full = (row0 + 128 <= M);
#pragma unroll
  for (int it = 0; it < 8; ++it) {
    int o = (it * 256 + t) * 8;
    int row = o >> 7;
    int gr = row0 + row;
    uint4 av = make_uint4(0, 0, 0, 0);
    if (full || gr < M) av = *(const uint4*)(T + (size_t)gr * 128 + (o & 127));
    int sw = o ^ ((row & 7) << 3);
    *(uint4*)(&As[sw]) = av;
  }
  __syncthreads();
  int wid = t >> 6, l = t & 63;
  int wr = wid >> 1, wc = wid & 1;
  int lr = l & 15, kb = l >> 4;
  f32x4 acc[4][4] = {};
#pragma unroll
  for (int ks = 0; ks < 4; ++ks) {
    half8 af[4], bfr[4];
#pragma unroll
    for (int m = 0; m < 4; ++m) {
      int row = wr * 64 + m * 16 + lr;
      int h2 = (row * 128 + kb * 8 + ks * 32) ^ ((row & 7) << 3);
      af[m] = *(half8*)(&As[h2]);
    }
#pragma unroll
    for (int n = 0; n < 4; ++n) {
      int row = wc * 64 + n * 16 + lr;
      bfr[n] = *(const half8*)(W + (size_t)row * 128 + kb * 8 + ks * 32);
    }
#pragma unroll
    for (int m = 0; m < 4; ++m)
#pragma unroll
      for (int n = 0; n < 4; ++n)
        acc[m][n] = __builtin_amdgcn_mfma_f32_16x16x32_f16(af[m], bfr[n], acc[m][n], 0, 0, 0);
  }
  float alpha = 1.0f / (1.0f + __expf(-skip[type]));
  float beta = 1.0f - alpha;
  int rb = row0 + wr * 64 + (l >> 4) * 4;
#pragma unroll
  for (int m = 0; m < 4; ++m)
#pragma unroll
    for (int jr = 0; jr < 4; ++jr) {
      int grow = rb + m * 16 + jr;
      if (grow < M) {
#pragma unroll
        for (int n = 0; n < 4; ++n) {
          int col = wc * 64 + n * 16 + lr;
          float vout = alpha * (acc[m][n][jr] + bias[col]) + beta * h[(size_t)grow * 128 + col];
          O[(size_t)grow * 128 + col] = vout;
        }
      }
    }
}

// ---------- CSR build: bucket hist, bin (local scan), padded per-bucket sort ----------

__global__ __launch_bounds__(256) void bhist_kernel(const int* __restrict__ d0,
                                                    const int* __restrict__ d1,
                                                    const int* __restrict__ d2,
                                                    int* __restrict__ bh, int E) {
  __shared__ int lh[NB];
  int r = blockIdx.y;
  const int* dst = r == 0 ? d0 : (r == 1 ? d1 : d2);
  int t = threadIdx.x;
  int lo = blockIdx.x * CHK;
  int hi = lo + CHK < E ? lo + CHK : E;
  for (int j = t; j < NB; j += 256) lh[j] = 0;
  __syncthreads();
  for (int i = lo + t; i < hi; i += 256) atomicAdd(&lh[dst[i] >> 8], 1);
  __syncthreads();
  for (int j = t; j < NB; j += 256) {
    int v = lh[j];
    if (v) atomicAdd(&bh[r * NB + j], v);
  }
}

__global__ __launch_bounds__(256) void bin_kernel(
    const int* __restrict__ s0, const int* __restrict__ d0, const int* __restrict__ s1,
    const int* __restrict__ d1, const int* __restrict__ s2, const int* __restrict__ d2,
    const int* __restrict__ bh, int* __restrict__ bcur, unsigned* __restrict__ bo0,
    unsigned* __restrict__ bo1, unsigned* __restrict__ bo2, int E) {
  __shared__ unsigned st[CHK];
  __shared__ int ga[CHK];
  __shared__ int hist[NB];
  __shared__ int scn[256];
  __shared__ int gb[NB];
  __shared__ int bbl[NB];
  int r = blockIdx.y;
  const int* src = r == 0 ? s0 : (r == 1 ? s1 : s2);
  const int* dst = r == 0 ? d0 : (r == 1 ? d1 : d2);
  unsigned* bo = r == 0 ? bo0 : (r == 1 ? bo1 : bo2);
  int t = threadIdx.x;
  // local exclusive scan of bucket totals -> bbl (replaces bscan kernel)
  {
    int v0 = (t < NB) ? bh[r * NB + t] : 0;
    scn[t] = v0;
    __syncthreads();
    for (int off = 1; off < 256; off <<= 1) {
      int u = (t >= off) ? scn[t - off] : 0;
      __syncthreads();
      scn[t] += u;
      __syncthreads();
    }
    if (t < NB) bbl[t] = scn[t] - v0;
    __syncthreads();
  }
  int lo = blockIdx.x * CHK;
  int hi = lo + CHK < E ? lo + CHK : E;
  int nloc = hi - lo;
  if (nloc <= 0) return;
  for (int j = t; j < NB; j += 256) hist[j] = 0;
  __syncthreads();
  int myb[CHK / 256], myr[CHK / 256];
  unsigned mye[CHK / 256];
#pragma unroll
  for (int k = 0; k < CHK / 256; ++k) {
    int i = lo + k * 256 + t;
    myb[k] = -1;
    if (i < hi) {
      int d = dst[i];
      int b = d >> 8;
      mye[k] = (unsigned)src[i] | ((unsigned)d << 16);
      myb[k] = b;
      myr[k] = atomicAdd(&hist[b], 1);
    }
  }
  __syncthreads();
  int v = (t < NB) ? hist[t] : 0;
  scn[t] = v;
  __syncthreads();
  for (int off = 1; off < 256; off <<= 1) {
    int u = (t >= off) ? scn[t - off] : 0;
    __syncthreads();
    scn[t] += u;
    __syncthreads();
  }
  int excl = scn[t] - v;
  __syncthreads();
  scn[t] = excl;
  if (t < NB && v > 0) gb[t] = atomicAdd(&bcur[r * NB + t], v);
  __syncthreads();
#pragma unroll
  for (int k = 0; k < CHK / 256; ++k) {
    if (myb[k] >= 0) {
      int slot = scn[myb[k]] + myr[k];
      st[slot] = mye[k];
      ga[slot] = bbl[myb[k]] + gb[myb[k]] + myr[k];
    }
  }
  __syncthreads();
  for (int j = t; j < nloc; j += 256) bo[ga[j]] = st[j];
}

// bsort: one block per bucket -> node-sorted, 8-padded packed array + rs/re
__global__ __launch_bounds__(256) void bsort_kernel(
    const unsigned* __restrict__ bo0, const unsigned* __restrict__ bo1,
    const unsigned* __restrict__ bo2, const int* __restrict__ bh, int* __restrict__ rs0,
    int* __restrict__ rs1, int* __restrict__ rs2, int* __restrict__ re0, int* __restrict__ re1,
    int* __restrict__ re2, unsigned* __restrict__ sp0, unsigned* __restrict__ sp1,
    unsigned* __restrict__ sp2, int nd0, int nd1, int nd2, int ns0, int ns1, int ns2, int E) {
  __shared__ unsigned ed[CAPB];
  __shared__ unsigned srt[PSTRIDE];
  __shared__ unsigned short rank[CAPB];
  __shared__ int hist[256];
  __shared__ int scn[256];
  __shared__ int bbl[NB + 1];
  int r = blockIdx.y, b = blockIdx.x;
  const unsigned* bo = r == 0 ? bo0 : (r == 1 ? bo1 : bo2);
  int* rs = r == 0 ? rs0 : (r == 1 ? rs1 : rs2);
  int* re = r == 0 ? re0 : (r == 1 ? re1 : re2);
  unsigned* sp = r == 0 ? sp0 : (r == 1 ? sp1 : sp2);
  int nd = r == 0 ? nd0 : (r == 1 ? nd1 : nd2);
  unsigned sentinel = (unsigned)(r == 0 ? ns0 : (r == 1 ? ns1 : ns2));
  int t = threadIdx.x;
  // local exclusive scan of bucket totals
  {
    int v0 = (t < NB) ? bh[r * NB + t] : 0;
    scn[t] = v0;
    __syncthreads();
    for (int off = 1; off < 256; off <<= 1) {
      int u = (t >= off) ? scn[t - off] : 0;
      __syncthreads();
      scn[t] += u;
      __syncthreads();
    }
    if (t < NB) bbl[t] = scn[t] - v0;
    if (t == 0) bbl[NB] = E;
    __syncthreads();
  }
  int base = bbl[b], endb = bbl[b + 1];
  int cnt = endb - base;
  if (cnt > CAPB) cnt = CAPB;
  int nlo = b << 8;
  int nn = nd - nlo;
  if (nn > 256) nn = 256;
  if (nn < 0) nn = 0;
  hist[t] = 0;
  for (int j = t; j < cnt; j += 256) ed[j] = bo[base + j];
  __syncthreads();
  for (int j = t; j < cnt; j += 256) {
    int node = (ed[j] >> 16) & 255;
    rank[j] = (unsigned short)atomicAdd(&hist[node], 1);
  }
  __syncthreads();
  int rawh = hist[t];
  int pd = (rawh + 7) & ~7;
  scn[t] = pd;
  __syncthreads();
  for (int off = 1; off < 256; off <<= 1) {
    int u = (t >= off) ? scn[t - off] : 0;
    __syncthreads();
    scn[t] += u;
    __syncthreads();
  }
  int pexcl = scn[t] - pd;
  int ptot = scn[255];
  __syncthreads();
  hist[t] = pexcl;
  __syncthreads();
  if (t < nn) {
    rs[nlo + t] = b * PSTRIDE + pexcl;
    re[nlo + t] = b * PSTRIDE + pexcl + rawh;  // RAW end in padded coords
  }
  int ptot32 = (ptot + 31) & ~31;
  for (int j = t; j < ptot32; j += 256) srt[j] = sentinel;  // pads -> zero-row src
  __syncthreads();
  for (int j = t; j < cnt; j += 256) {
    int node = (ed[j] >> 16) & 255;
    srt[hist[node] + rank[j]] = ed[j];
  }
  __syncthreads();
  unsigned* spb = sp + (size_t)b * PSTRIDE;
  for (int j = t; j < ptot32; j += 256) spb[j] = srt[j];
}

// ---------- fused edge pass: per node, inline score + softmax-weighted aggregate ----------
struct FuP {
  const unsigned *sp0, *sp1, *sp2;
  const unsigned *kv0, *kv1, *kv2;
  const unsigned *qb0, *qb1;
  const int *rs0, *rs1, *rs2;
  const int *re0, *re1, *re2;
  unsigned *Tb0, *Tb1;
  int N0, N1;
};

__device__ __forceinline__ void loadRows(const char* __restrict__ kvlk,
                                         const char* __restrict__ kvlv, unsigned sv, int half,
                                         uint2 kf[4], uint2 vf[4]) {
#pragma unroll
  for (int g = 0; g < 4; ++g) {
    unsigned pA = __builtin_amdgcn_readlane(sv, g);
    unsigned pB = __builtin_amdgcn_readlane(sv, g + 4);
    unsigned pk = half ? pB : pA;
    size_t off = (size_t)(pk & 0xFFFFu) << 9;
    kf[g] = *(const uint2*)(kvlk + off);
    vf[g] = *(const uint2*)(kvlv + off);
  }
}

__device__ __forceinline__ void computeKV(const uint2 kf[4], const uint2 vf[4], unsigned qx,
                                          unsigned qy, float& a0, float& a1, float& a2,
                                          float& a3, float& den) {
#pragma unroll
  for (int g = 0; g < 4; ++g) {
    float sc = fdot2(kf[g].y, qy, fdot2(kf[g].x, qx, 0.f));
    sc = DPPADD(sc, 0xB1);  // xor1
    sc = DPPADD(sc, 0x4E);  // xor2 -> full 16-dim head dot
    float e = __expf(sc);
    den += e;
    unsigned eu = f2h(e);
    unsigned pl = eu;        // (e, 0)
    unsigned ph = eu << 16;  // (0, e)
    a0 = fdot2(vf[g].x, pl, a0);
    a1 = fdot2(vf[g].x, ph, a1);
    a2 = fdot2(vf[g].y, pl, a2);
    a3 = fdot2(vf[g].y, ph, a3);
  }
}

__device__ __forceinline__ void fuse_rel(const unsigned* __restrict__ sp,
                                         const unsigned* __restrict__ kv,
                                         const int* __restrict__ rs, const int* __restrict__ re,
                                         int node, int ll, int half, unsigned qx, unsigned qy,
                                         float& r0, float& r1, float& r2, float& r3) {
  int beg = __builtin_amdgcn_readfirstlane(rs[node]);
  int rend = __builtin_amdgcn_readfirstlane(re[node]);
  int raw = rend - beg;
  if (raw <= 0) return;
  int pd = (raw + 7) & ~7;
  int end = beg + pd;
  float npad = (float)(pd - raw);
  const char* kvlk = (const char*)kv + ll * 8;
  const char* kvlv = (const char*)kv + 256 + ll * 8;
  float a0 = 0.f, a1 = 0.f, a2 = 0.f, a3 = 0.f, den = 0.f;
  uint2 ka[4], va[4], kb2[4], vb2[4];
  int lane7 = threadIdx.x & 7;
  int p = beg;
  unsigned svA = sp[p + lane7];
  loadRows(kvlk, kvlv, svA, half, ka, va);
  unsigned svB = sp[p + 8 + lane7];  // may read past run (workspace-safe), unused if pd==8
  for (;;) {
    if (p + 8 < end) loadRows(kvlk, kvlv, svB, half, kb2, vb2);
    svA = sp[p + 16 + lane7];  // prefetch sp two batches ahead
    computeKV(ka, va, qx, qy, a0, a1, a2, a3, den);
    p += 8;
    if (p >= end) break;
    if (p + 8 < end) loadRows(kvlk, kvlv, svA, half, ka, va);
    svB = sp[p + 16 + lane7];
    computeKV(kb2, vb2, qx, qy, a0, a1, a2, a3, den);
    p += 8;
    if (p >= end) break;
  }
  den += __shfl_xor(den, 32);
  a0 += __shfl_xor(a0, 32);
  a1 += __shfl_xor(a1, 32);
  a2 += __shfl_xor(a2, 32);
  a3 += __shfl_xor(a3, 32);
  den -= npad;  // pads contributed exp(0)=1 each
  float inv = 1.0f / den;
  r0 = fmaf(a0, inv, r0);
  r1 = fmaf(a1, inv, r1);
  r2 = fmaf(a2, inv, r2);
  r3 = fmaf(a3, inv, r3);
}

__global__ __launch_bounds__(256) void fusedge_kernel(FuP P) {
  int gw = (blockIdx.x * 256 + threadIdx.x) >> 6;
  int l = threadIdx.x & 63;
  int ll = l & 31, half = l >> 5;
  if (gw < P.N0) {
    uint2 q = *(const uint2*)((const char*)P.qb0 + (size_t)gw * 256 + ll * 8);
    float r0 = 0.f, r1 = 0.f, r2 = 0.f, r3 = 0.f;
    fuse_rel(P.sp1, P.kv1, P.rs1, P.re1, gw, ll, half, q.x, q.y, r0, r1, r2, r3);
    fuse_rel(P.sp2, P.kv2, P.rs2, P.re2, gw, ll, half, q.x, q.y, r0, r1, r2, r3);
    if (half == 0) {
      uint2 o;
      o.x = f2h(r0 * 0.5f) | ((unsigned)f2h(r1 * 0.5f) << 16);
      o.y = f2h(r2 * 0.5f) | ((unsigned)f2h(r3 * 0.5f) << 16);
      *(uint2*)(P.Tb0 + (size_t)gw * 64 + 2 * ll) = o;
    }
  } else if (gw < P.N0 + P.N1) {
    int n = gw - P.N0;
    uint2 q = *(const uint2*)((const char*)P.qb1 + (size_t)n * 256 + ll * 8);
    float r0 = 0.f, r1 = 0.f, r2 = 0.f, r3 = 0.f;
    fuse_rel(P.sp0, P.kv0, P.rs0, P.re0, n, ll, half, q.x, q.y, r0, r1, r2, r3);
    if (half == 0) {
      uint2 o;
      o.x = f2h(r0) | ((unsigned)f2h(r1) << 16);
      o.y = f2h(r2) | ((unsigned)f2h(r3) << 16);
      *(uint2*)(P.Tb1 + (size_t)n * 64 + 2 * ll) = o;
    }
  }
}

// ---------- host ----------
extern "C" void kernel_launch(void* const* d_in, const int* in_sizes, int n_in,
                              void* d_out, int out_size, void* d_ws, size_t ws_size,
                              hipStream_t stream) {
  const float* h0 = (const float*)d_in[0];
  const float* h1 = (const float*)d_in[1];
  const int* srcs[3] = {(const int*)d_in[2], (const int*)d_in[4], (const int*)d_in[6]};
  const int* dsts[3] = {(const int*)d_in[3], (const int*)d_in[5], (const int*)d_in[7]};
  const float* Wk = (const float*)d_in[8];
  const float* bk = (const float*)d_in[9];
  const float* Wq = (const float*)d_in[10];
  const float* bq = (const float*)d_in[11];
  const float* Wv = (const float*)d_in[12];
  const float* bv = (const float*)d_in[13];
  const float* Wa = (const float*)d_in[14];
  const float* ba = (const float*)d_in[15];
  const float* rel_att = (const float*)d_in[16];
  const float* rel_msg = (const float*)d_in[17];
  const float* rel_pri = (const float*)d_in[18];
  const float* skip = (const float*)d_in[19];

  int N0 = in_sizes[0] / 128;
  int N1 = in_sizes[1] / 128;
  int E = in_sizes[2];
  int nsrc[3] = {N0, N1, N0};
  int ndst[3] = {N1, N0, N0};
  int maxN = N0 > N1 ? N0 : N1;

  char* base = (char*)d_ws;
  size_t off = 0;
  auto alloc = [&](size_t bytes) -> void* {
    void* p = base + off;
    off += (bytes + 255) & ~(size_t)255;
    return p;
  };

  unsigned short* qb0 = (unsigned short*)alloc((size_t)N0 * 128 * 2);
  unsigned short* qb1 = (unsigned short*)alloc((size_t)N1 * 128 * 2);
  unsigned short* kvb[3];  // interleaved [N+1][kr(128) | vr(128)] f16; last row = zeros
  for (int r = 0; r < 3; ++r) kvb[r] = (unsigned short*)alloc((size_t)(nsrc[r] + 1) * 256 * 2);
  unsigned short* Tb0 = (unsigned short*)alloc((size_t)N0 * 128 * 2);
  unsigned short* Tb1 = (unsigned short*)alloc((size_t)N1 * 128 * 2);
  unsigned short* Wkrb = (unsigned short*)alloc((size_t)3 * 16384 * 2);
  unsigned short* Wvrb = (unsigned short*)alloc((size_t)3 * 16384 * 2);
  unsigned short* Wqb = (unsigned short*)alloc((size_t)2 * 16384 * 2);
  unsigned short* Wab = (unsigned short*)alloc((size_t)2 * 16384 * 2);
  float* bkr = (float*)alloc(3 * 128 * 4);
  float* bvr = (float*)alloc(3 * 128 * 4);
  int* rp_s[3];
  int* rp_e[3];
  unsigned* spk[3];
  unsigned* bo[3];
  for (int r = 0; r < 3; ++r) {
    rp_s[r] = (int*)alloc((size_t)ndst[r] * 4);
    rp_e[r] = (int*)alloc((size_t)ndst[r] * 4);
    spk[r] = (unsigned*)alloc((size_t)NB * PSTRIDE * 4);
    bo[r] = (unsigned*)alloc((size_t)(E + 64) * 4);
  }
  int* bcnt = (int*)alloc((size_t)2 * 3 * NB * 4);  // bhist | bcur
  int* bhist = bcnt;
  int* bcur = bcnt + 3 * NB;
  (void)ws_size;

  // 1. weight prep (+ zero pad-rows folded into cvt2)
  compose_w_kernel<<<dim3(3, 128, 2), 128, 0, stream>>>(Wk, bk, Wv, bv, rel_att, rel_msg,
                                                        rel_pri, Wkrb, bkr, Wvrb, bvr);
  cvt2_kernel<<<dim3(16, 3), 256, 0, stream>>>(Wq, Wqb, Wa, Wab, 4096,
                                               kvb[0] + (size_t)nsrc[0] * 256,
                                               kvb[1] + (size_t)nsrc[1] * 256,
                                               kvb[2] + (size_t)nsrc[2] * 256);

  // 2. fused projection GEMMs -> f16 q + interleaved kv tables
  ProjFP pf;
  pf.A[0] = h0; pf.A[1] = h1;
  pf.M[0] = N0; pf.M[1] = N1;
  pf.nj[0] = 5; pf.nj[1] = 3;
  pf.W[0] = Wqb;            pf.b[0] = bq;        pf.out[0] = qb0;          pf.ostr[0] = 128;
  pf.W[1] = Wkrb;           pf.b[1] = bkr;       pf.out[1] = kvb[0];       pf.ostr[1] = 256;
  pf.W[2] = Wkrb + 32768;   pf.b[2] = bkr + 256; pf.out[2] = kvb[2];       pf.ostr[2] = 256;
  pf.W[3] = Wvrb;           pf.b[3] = bvr;       pf.out[3] = kvb[0] + 128; pf.ostr[3] = 256;
  pf.W[4] = Wvrb + 32768;   pf.b[4] = bvr + 256; pf.out[4] = kvb[2] + 128; pf.ostr[4] = 256;
  pf.W[5] = Wqb + 16384;    pf.b[5] = bq + 128;  pf.out[5] = qb1;          pf.ostr[5] = 128;
  pf.W[6] = Wkrb + 16384;   pf.b[6] = bkr + 128; pf.out[6] = kvb[1];       pf.ostr[6] = 256;
  pf.W[7] = Wvrb + 16384;   pf.b[7] = bvr + 128; pf.out[7] = kvb[1] + 128; pf.ostr[7] = 256;
  pf.W[8] = Wqb; pf.b[8] = bq; pf.out[8] = qb0; pf.ostr[8] = 128;  // unused
  pf.W[9] = Wqb; pf.b[9] = bq; pf.out[9] = qb0; pf.ostr[9] = 128;  // unused
  proj_gemm_fused<<<dim3((maxN + 127) / 128, 2), 256, 0, stream>>>(pf);

  // 3. CSR via 2-level LDS-staged counting sort with 8-padded node runs
  hipMemsetAsync(bcnt, 0, (size_t)2 * 3 * NB * 4, stream);
  bhist_kernel<<<dim3((E + CHK - 1) / CHK, 3), 256, 0, stream>>>(dsts[0], dsts[1], dsts[2],
                                                                 bhist, E);
  bin_kernel<<<dim3((E + CHK - 1) / CHK, 3), 256, 0, stream>>>(
      srcs[0], dsts[0], srcs[1], dsts[1], srcs[2], dsts[2], bhist, bcur, bo[0], bo[1], bo[2], E);
  bsort_kernel<<<dim3(NB, 3), 256, 0, stream>>>(
      bo[0], bo[1], bo[2], bhist, rp_s[0], rp_s[1], rp_s[2], rp_e[0], rp_e[1], rp_e[2],
      spk[0], spk[1], spk[2], ndst[0], ndst[1], ndst[2], nsrc[0], nsrc[1], nsrc[2], E);

  // 4. fused edge pass (score + softmax + aggregate) -> f16 T
  FuP fp2;
  fp2.sp0 = spk[0]; fp2.sp1 = spk[1]; fp2.sp2 = spk[2];
  fp2.kv0 = (const unsigned*)kvb[0]; fp2.kv1 = (const unsigned*)kvb[1];
  fp2.kv2 = (const unsigned*)kvb[2];
  fp2.qb0 = (const unsigned*)qb0; fp2.qb1 = (const unsigned*)qb1;
  fp2.rs0 = rp_s[0]; fp2.rs1 = rp_s[1]; fp2.rs2 = rp_s[2];
  fp2.re0 = rp_e[0]; fp2.re1 = rp_e[1]; fp2.re2 = rp_e[2];
  fp2.Tb0 = (unsigned*)Tb0; fp2.Tb1 = (unsigned*)Tb1;
  fp2.N0 = N0; fp2.N1 = N1;
  int totw = N0 + N1;
  fusedge_kernel<<<(totw + 3) / 4, 256, 0, stream>>>(fp2);

  // 5. final GEMM + skip blend -> fp32 d_out
  final_gemm_mfma<<<dim3((maxN + 127) / 128, 2), 256, 0, stream>>>(
      (float*)d_out, Tb0, Tb1, Wab, ba, h0, h1, skip, N0, N1);
}

// Round 15
// 226.244 us; speedup vs baseline: 1.1177x; 1.1177x over previous
//
#include <hip/hip_runtime.h>

typedef __attribute__((ext_vector_type(8))) _Float16 half8;
typedef __attribute__((ext_vector_type(2))) _Float16 half2v;
typedef __attribute__((ext_vector_type(4))) float f32x4;

#define NB 196       // dst buckets per relation (bucket width 256 nodes)
#define CHK 2048     // edges per bin/bhist block
#define CAPB 4096    // max raw edges per bucket (mean ~2551)
#define PSTRIDE 6144 // padded slots per bucket

// ---------- helpers ----------
__device__ __forceinline__ unsigned short f2h(float f) {
  _Float16 h = (_Float16)f;
  return __builtin_bit_cast(unsigned short, h);
}
__device__ __forceinline__ float fdot2(unsigned a, unsigned b, float c) {
  return __builtin_amdgcn_fdot2(__builtin_bit_cast(half2v, a), __builtin_bit_cast(half2v, b), c,
                                false);
}

#define DPPADD(v, ctrl) \
  ((v) + __int_as_float(__builtin_amdgcn_update_dpp(0, __float_as_int(v), ctrl, 0xF, 0xF, true)))

// ---------- fp32 -> f16 bulk convert (2 arrays) + zero-row init ----------
__global__ void cvt2_kernel(const float* __restrict__ a, unsigned short* __restrict__ oa,
                            const float* __restrict__ b, unsigned short* __restrict__ ob,
                            int n8, unsigned short* __restrict__ z0,
                            unsigned short* __restrict__ z1, unsigned short* __restrict__ z2) {
  int t = threadIdx.x;
  if (blockIdx.y == 2) {
    if (blockIdx.x == 0 && t < 192) {
      int r = t >> 6;
      unsigned short* z = r == 0 ? z0 : (r == 1 ? z1 : z2);
      ((uint2*)z)[t & 63] = make_uint2(0, 0);
    }
    return;
  }
  int i = blockIdx.x * 256 + t;
  if (i >= n8) return;
  const float* in = blockIdx.y ? b : a;
  unsigned short* out = blockIdx.y ? ob : oa;
  const float4* p = (const float4*)(in + (size_t)i * 8);
  float4 x = p[0], y = p[1];
  uint4 v;
  v.x = f2h(x.x) | ((unsigned)f2h(x.y) << 16);
  v.y = f2h(x.z) | ((unsigned)f2h(x.w) << 16);
  v.z = f2h(y.x) | ((unsigned)f2h(y.y) << 16);
  v.w = f2h(y.z) | ((unsigned)f2h(y.w) << 16);
  *(uint4*)(out + (size_t)i * 8) = v;
}

// ---------- composed relation weights (f16 out, fp32 bias) ----------
__global__ void compose_w_kernel(const float* __restrict__ Wk, const float* __restrict__ bk,
                                 const float* __restrict__ Wv, const float* __restrict__ bv,
                                 const float* __restrict__ rel_att, const float* __restrict__ rel_msg,
                                 const float* __restrict__ rel_pri,
                                 unsigned short* __restrict__ Wkr, float* __restrict__ bkr,
                                 unsigned short* __restrict__ Wvr, float* __restrict__ bvr) {
  int e = blockIdx.x;
  int o = blockIdx.y;
  int z = blockIdx.z;
  int c = threadIdx.x;
  int hd = o >> 4, j = o & 15;
  const int se[3] = {0, 1, 0};
  int s = se[e];
  const float* W = z ? Wv : Wk;
  const float* b = z ? bv : bk;
  const float* R = z ? rel_msg : rel_att;
  float scale = z ? 1.0f : (rel_pri[e * 8 + hd] * 0.25f);
  float acc = 0.0f, bacc = 0.0f;
#pragma unroll
  for (int i = 0; i < 16; ++i) {
    float r = R[((e * 8 + hd) * 16 + i) * 16 + j];
    acc += W[(s * 128 + hd * 16 + i) * 128 + c] * r;
    bacc += b[s * 128 + hd * 16 + i] * r;
  }
  unsigned short* Wo = z ? Wvr : Wkr;
  float* bo = z ? bvr : bkr;
  Wo[((size_t)e * 128 + o) * 128 + c] = f2h(acc * scale);
  if (c == 0) bo[e * 128 + o] = bacc * scale;
}

// ---------- combined: proj GEMMs (y=0,1) + bucket histogram (y=2,3,4) ----------
struct ProjFP {
  const float* A[2];
  int M[2];
  int nj[2];
  const unsigned short* W[10];
  const float* b[10];
  unsigned short* out[10];
  int ostr[10];
  const int* dst[3];
  int* bh;
  int E;
};

__global__ __launch_bounds__(256) void proj_bhist_kernel(ProjFP P) {
  __shared__ short As[128 * 128];
  __shared__ short Bs[128 * 128];
  __shared__ int lh[NB];
  int t = threadIdx.x;
  if (blockIdx.y >= 2) {
    // ---- bucket histogram path ----
    int r = blockIdx.y - 2;
    int nbh = (P.E + CHK - 1) / CHK;
    if (blockIdx.x >= nbh) return;
    const int* dst = P.dst[r];
    int lo = blockIdx.x * CHK;
    int hi = lo + CHK < P.E ? lo + CHK : P.E;
    for (int j = t; j < NB; j += 256) lh[j] = 0;
    __syncthreads();
    for (int i = lo + t; i < hi; i += 256) atomicAdd(&lh[dst[i] >> 8], 1);
    __syncthreads();
    for (int j = t; j < NB; j += 256) {
      int v = lh[j];
      if (v) atomicAdd(&P.bh[r * NB + j], v);
    }
    return;
  }
  // ---- projection GEMM path ----
  int type = blockIdx.y;
  const float* __restrict__ A = P.A[type];
  int M = P.M[type];
  int nj = P.nj[type];
  int base = type * 5;
  int row0 = blockIdx.x * 128;
  if (row0 >= M) return;
  bool full = (row0 + 128 <= M);
#pragma unroll
  for (int it = 0; it < 8; ++it) {
    int o = (it * 256 + t) * 8;
    int row = o >> 7, col = o & 127;
    int gr = row0 + row;
    uint4 av = make_uint4(0, 0, 0, 0);
    if (full || gr < M) {
      float4 x = *(const float4*)(A + (size_t)gr * 128 + col);
      float4 y = *(const float4*)(A + (size_t)gr * 128 + col + 4);
      av.x = f2h(x.x) | ((unsigned)f2h(x.y) << 16);
      av.y = f2h(x.z) | ((unsigned)f2h(x.w) << 16);
      av.z = f2h(y.x) | ((unsigned)f2h(y.y) << 16);
      av.w = f2h(y.z) | ((unsigned)f2h(y.w) << 16);
    }
    int sw = o ^ ((row & 7) << 3);
    *(uint4*)(&As[sw]) = av;
  }
  {
    const unsigned short* W0 = P.W[base];
#pragma unroll
    for (int it = 0; it < 8; ++it) {
      int o = (it * 256 + t) * 8;
      int row = o >> 7;
      int sw = o ^ ((row & 7) << 3);
      *(uint4*)(&Bs[sw]) = *(const uint4*)(W0 + o);
    }
  }
  __syncthreads();
  int wid = t >> 6, l = t & 63;
  int wr = wid >> 1, wc = wid & 1;
  int lr = l & 15, kb = l >> 4;
  for (int j = 0;; ++j) {
    f32x4 acc[4][4] = {};
#pragma unroll
    for (int ks = 0; ks < 4; ++ks) {
      half8 af[4], bfr[4];
#pragma unroll
      for (int m = 0; m < 4; ++m) {
        int row = wr * 64 + m * 16 + lr;
        int h = (row * 128 + kb * 8 + ks * 32) ^ ((row & 7) << 3);
        af[m] = *(half8*)(&As[h]);
      }
#pragma unroll
      for (int n = 0; n < 4; ++n) {
        int row = wc * 64 + n * 16 + lr;
        int h = (row * 128 + kb * 8 + ks * 32) ^ ((row & 7) << 3);
        bfr[n] = *(half8*)(&Bs[h]);
      }
#pragma unroll
      for (int m = 0; m < 4; ++m)
#pragma unroll
        for (int n = 0; n < 4; ++n)
          acc[m][n] = __builtin_amdgcn_mfma_f32_16x16x32_f16(af[m], bfr[n], acc[m][n], 0, 0, 0);
    }
    const float* bias = P.b[base + j];
    unsigned short* out = P.out[base + j];
    int ostr = P.ostr[base + j];
    int rb = row0 + wr * 64 + (l >> 4) * 4;
#pragma unroll
    for (int m = 0; m < 4; ++m)
#pragma unroll
      for (int jr = 0; jr < 4; ++jr) {
        int grow = rb + m * 16 + jr;
        if (grow < M) {
#pragma unroll
          for (int n = 0; n < 4; ++n) {
            int col = wc * 64 + n * 16 + lr;
            out[(size_t)grow * ostr + col] = f2h(acc[m][n][jr] + bias[col]);
          }
        }
      }
    if (j + 1 >= nj) break;
    __syncthreads();
    {
      const unsigned short* Wj = P.W[base + j + 1];
#pragma unroll
      for (int it = 0; it < 8; ++it) {
        int o = (it * 256 + t) * 8;
        int row = o >> 7;
        int sw = o ^ ((row & 7) << 3);
        *(uint4*)(&Bs[sw]) = *(const uint4*)(Wj + o);
      }
    }
    __syncthreads();
  }
}

// ---------- MFMA final GEMM (f16 inputs, fp32 out) ----------
__global__ __launch_bounds__(256) void final_gemm_mfma(
    float* __restrict__ dout, const unsigned short* __restrict__ Tb0,
    const unsigned short* __restrict__ Tb1, const unsigned short* __restrict__ Wab,
    const float* __restrict__ ba, const float* __restrict__ h0, const float* __restrict__ h1,
    const float* __restrict__ skip, int N0, int N1) {
  __shared__ short As[128 * 128];
  __shared__ short Bs[128 * 128];
  int type = blockIdx.y;
  int M = type ? N1 : N0;
  const unsigned short* T = type ? Tb1 : Tb0;
  const unsigned short* W = Wab + (size_t)type * 16384;
  const float* bias = ba + type * 128;
  const float* h = type ? h1 : h0;
  float* O = dout + (type ? (size_t)N0 * 128 : 0);
  int row0 = blockIdx.x * 128;
  if (row0 >= M) return;
  int t = threadIdx.x;
  bool full = (row0 + 128 <= M);
#pragma unroll
  for (int it = 0; it < 8; ++it) {
    int o = (it * 256 + t) * 8;
    int row = o >> 7;
    int gr = row0 + row;
    uint4 av = make_uint4(0, 0, 0, 0);
    if (full || gr < M) av = *(const uint4*)(T + (size_t)gr * 128 + (o & 127));
    int sw = o ^ ((row & 7) << 3);
    *(uint4*)(&As[sw]) = av;
    uint4 wv = *(const uint4*)(W + o);
    *(uint4*)(&Bs[sw]) = wv;
  }
  __syncthreads();
  int wid = t >> 6, l = t & 63;
  int wr = wid >> 1, wc = wid & 1;
  int lr = l & 15, kb = l >> 4;
  f32x4 acc[4][4] = {};
#pragma unroll
  for (int ks = 0; ks < 4; ++ks) {
    half8 af[4], bfr[4];
#pragma unroll
    for (int m = 0; m < 4; ++m) {
      int row = wr * 64 + m * 16 + lr;
      int h2 = (row * 128 + kb * 8 + ks * 32) ^ ((row & 7) << 3);
      af[m] = *(half8*)(&As[h2]);
    }
#pragma unroll
    for (int n = 0; n < 4; ++n) {
      int row = wc * 64 + n * 16 + lr;
      int h2 = (row * 128 + kb * 8 + ks * 32) ^ ((row & 7) << 3);
      bfr[n] = *(half8*)(&Bs[h2]);
    }
#pragma unroll
    for (int m = 0; m < 4; ++m)
#pragma unroll
      for (int n = 0; n < 4; ++n)
        acc[m][n] = __builtin_amdgcn_mfma_f32_16x16x32_f16(af[m], bfr[n], acc[m][n], 0, 0, 0);
  }
  float alpha = 1.0f / (1.0f + __expf(-skip[type]));
  float beta = 1.0f - alpha;
  int rb = row0 + wr * 64 + (l >> 4) * 4;
#pragma unroll
  for (int m = 0; m < 4; ++m)
#pragma unroll
    for (int jr = 0; jr < 4; ++jr) {
      int grow = rb + m * 16 + jr;
      if (grow < M) {
#pragma unroll
        for (int n = 0; n < 4; ++n) {
          int col = wc * 64 + n * 16 + lr;
          float vout = alpha * (acc[m][n][jr] + bias[col]) + beta * h[(size_t)grow * 128 + col];
          O[(size_t)grow * 128 + col] = vout;
        }
      }
    }
}

// ---------- CSR: bin (local bucket scan) + padded per-bucket sort ----------

__global__ __launch_bounds__(256) void bin_kernel(
    const int* __restrict__ s0, const int* __restrict__ d0, const int* __restrict__ s1,
    const int* __restrict__ d1, const int* __restrict__ s2, const int* __restrict__ d2,
    const int* __restrict__ bh, int* __restrict__ bcur, unsigned* __restrict__ bo0,
    unsigned* __restrict__ bo1, unsigned* __restrict__ bo2, int E) {
  __shared__ unsigned st[CHK];
  __shared__ int ga[CHK];
  __shared__ int hist[NB];
  __shared__ int scn[256];
  __shared__ int gb[NB];
  __shared__ int bbl[NB];
  int r = blockIdx.y;
  const int* src = r == 0 ? s0 : (r == 1 ? s1 : s2);
  const int* dst = r == 0 ? d0 : (r == 1 ? d1 : d2);
  unsigned* bo = r == 0 ? bo0 : (r == 1 ? bo1 : bo2);
  int t = threadIdx.x;
  // local exclusive scan of bucket totals (replaces bscan kernel)
  {
    int v0 = (t < NB) ? bh[r * NB + t] : 0;
    scn[t] = v0;
    __syncthreads();
    for (int off = 1; off < 256; off <<= 1) {
      int u = (t >= off) ? scn[t - off] : 0;
      __syncthreads();
      scn[t] += u;
      __syncthreads();
    }
    if (t < NB) bbl[t] = scn[t] - v0;
    __syncthreads();
  }
  int lo = blockIdx.x * CHK;
  int hi = lo + CHK < E ? lo + CHK : E;
  int nloc = hi - lo;
  if (nloc <= 0) return;
  for (int j = t; j < NB; j += 256) hist[j] = 0;
  __syncthreads();
  int myb[CHK / 256], myr[CHK / 256];
  unsigned mye[CHK / 256];
#pragma unroll
  for (int k = 0; k < CHK / 256; ++k) {
    int i = lo + k * 256 + t;
    myb[k] = -1;
    if (i < hi) {
      int d = dst[i];
      int b = d >> 8;
      mye[k] = (unsigned)src[i] | ((unsigned)d << 16);
      myb[k] = b;
      myr[k] = atomicAdd(&hist[b], 1);
    }
  }
  __syncthreads();
  int v = (t < NB) ? hist[t] : 0;
  scn[t] = v;
  __syncthreads();
  for (int off = 1; off < 256; off <<= 1) {
    int u = (t >= off) ? scn[t - off] : 0;
    __syncthreads();
    scn[t] += u;
    __syncthreads();
  }
  int excl = scn[t] - v;
  __syncthreads();
  scn[t] = excl;
  if (t < NB && v > 0) gb[t] = atomicAdd(&bcur[r * NB + t], v);
  __syncthreads();
#pragma unroll
  for (int k = 0; k < CHK / 256; ++k) {
    if (myb[k] >= 0) {
      int slot = scn[myb[k]] + myr[k];
      st[slot] = mye[k];
      ga[slot] = bbl[myb[k]] + gb[myb[k]] + myr[k];
    }
  }
  __syncthreads();
  for (int j = t; j < nloc; j += 256) bo[ga[j]] = st[j];
}

// bsort: one block per bucket -> node-sorted, 8-padded packed array + rs/re
__global__ __launch_bounds__(256) void bsort_kernel(
    const unsigned* __restrict__ bo0, const unsigned* __restrict__ bo1,
    const unsigned* __restrict__ bo2, const int* __restrict__ bh, int* __restrict__ rs0,
    int* __restrict__ rs1, int* __restrict__ rs2, int* __restrict__ re0, int* __restrict__ re1,
    int* __restrict__ re2, unsigned* __restrict__ sp0, unsigned* __restrict__ sp1,
    unsigned* __restrict__ sp2, int nd0, int nd1, int nd2, int ns0, int ns1, int ns2, int E) {
  __shared__ unsigned ed[CAPB];
  __shared__ unsigned srt[PSTRIDE];
  __shared__ unsigned short rank[CAPB];
  __shared__ int hist[256];
  __shared__ int scn[256];
  __shared__ int bbl[NB + 1];
  int r = blockIdx.y, b = blockIdx.x;
  const unsigned* bo = r == 0 ? bo0 : (r == 1 ? bo1 : bo2);
  int* rs = r == 0 ? rs0 : (r == 1 ? rs1 : rs2);
  int* re = r == 0 ? re0 : (r == 1 ? re1 : re2);
  unsigned* sp = r == 0 ? sp0 : (r == 1 ? sp1 : sp2);
  int nd = r == 0 ? nd0 : (r == 1 ? nd1 : nd2);
  unsigned sentinel = (unsigned)(r == 0 ? ns0 : (r == 1 ? ns1 : ns2));
  int t = threadIdx.x;
  {
    int v0 = (t < NB) ? bh[r * NB + t] : 0;
    scn[t] = v0;
    __syncthreads();
    for (int off = 1; off < 256; off <<= 1) {
      int u = (t >= off) ? scn[t - off] : 0;
      __syncthreads();
      scn[t] += u;
      __syncthreads();
    }
    if (t < NB) bbl[t] = scn[t] - v0;
    if (t == 0) bbl[NB] = E;
    __syncthreads();
  }
  int base = bbl[b], endb = bbl[b + 1];
  int cnt = endb - base;
  if (cnt > CAPB) cnt = CAPB;
  int nlo = b << 8;
  int nn = nd - nlo;
  if (nn > 256) nn = 256;
  if (nn < 0) nn = 0;
  hist[t] = 0;
  for (int j = t; j < cnt; j += 256) ed[j] = bo[base + j];
  __syncthreads();
  for (int j = t; j < cnt; j += 256) {
    int node = (ed[j] >> 16) & 255;
    rank[j] = (unsigned short)atomicAdd(&hist[node], 1);
  }
  __syncthreads();
  int rawh = hist[t];
  int pd = (rawh + 7) & ~7;
  scn[t] = pd;
  __syncthreads();
  for (int off = 1; off < 256; off <<= 1) {
    int u = (t >= off) ? scn[t - off] : 0;
    __syncthreads();
    scn[t] += u;
    __syncthreads();
  }
  int pexcl = scn[t] - pd;
  int ptot = scn[255];
  __syncthreads();
  hist[t] = pexcl;
  __syncthreads();
  if (t < nn) {
    rs[nlo + t] = b * PSTRIDE + pexcl;
    re[nlo + t] = b * PSTRIDE + pexcl + rawh;  // RAW end in padded coords
  }
  int ptot32 = (ptot + 31) & ~31;
  for (int j = t; j < ptot32; j += 256) srt[j] = sentinel;  // pads -> zero-row src
  __syncthreads();
  for (int j = t; j < cnt; j += 256) {
    int node = (ed[j] >> 16) & 255;
    srt[hist[node] + rank[j]] = ed[j];
  }
  __syncthreads();
  unsigned* spb = sp + (size_t)b * PSTRIDE;
  for (int j = t; j < ptot32; j += 256) spb[j] = srt[j];
}

// ---------- fused edge pass: per node, inline score + softmax-weighted aggregate ----------
struct FuP {
  const unsigned *sp0, *sp1, *sp2;
  const unsigned *kv0, *kv1, *kv2;
  const unsigned *qb0, *qb1;
  const int *rs0, *rs1, *rs2;
  const int *re0, *re1, *re2;
  unsigned *Tb0, *Tb1;
  int N0, N1;
};

__device__ __forceinline__ void loadKV(const char* __restrict__ kvl,
                                       const unsigned* __restrict__ sp, int p, int half,
                                       uint2 kf[4], uint2 vf[4]) {
  unsigned sv = sp[p + (threadIdx.x & 7)];
#pragma unroll
  for (int g = 0; g < 4; ++g) {
    unsigned pA = __builtin_amdgcn_readlane(sv, g);
    unsigned pB = __builtin_amdgcn_readlane(sv, g + 4);
    unsigned pk = half ? pB : pA;
    const char* row = kvl + ((size_t)(pk & 0xFFFFu) << 9);
    kf[g] = *(const uint2*)row;
    vf[g] = *(const uint2*)(row + 256);
  }
}

__device__ __forceinline__ void computeKV(const uint2 kf[4], const uint2 vf[4], unsigned qx,
                                          unsigned qy, float& a0, float& a1, float& a2,
                                          float& a3, float& den) {
#pragma unroll
  for (int g = 0; g < 4; ++g) {
    float sc = fdot2(kf[g].y, qy, fdot2(kf[g].x, qx, 0.f));
    sc = DPPADD(sc, 0xB1);  // xor1
    sc = DPPADD(sc, 0x4E);  // xor2 -> full 16-dim head dot
    float e = __expf(sc);
    den += e;
    unsigned eu = f2h(e);
    unsigned pl = eu;        // (e, 0)
    unsigned ph = eu << 16;  // (0, e)
    a0 = fdot2(vf[g].x, pl, a0);
    a1 = fdot2(vf[g].x, ph, a1);
    a2 = fdot2(vf[g].y, pl, a2);
    a3 = fdot2(vf[g].y, ph, a3);
  }
}

__device__ __forceinline__ void fuse_rel(const unsigned* __restrict__ sp,
                                         const unsigned* __restrict__ kv,
                                         const int* __restrict__ rs, const int* __restrict__ re,
                                         int node, int ll, int half, unsigned qx, unsigned qy,
                                         float& r0, float& r1, float& r2, float& r3) {
  int beg = __builtin_amdgcn_readfirstlane(rs[node]);
  int rend = __builtin_amdgcn_readfirstlane(re[node]);
  int raw = rend - beg;
  if (raw <= 0) return;
  int pd = (raw + 7) & ~7;
  int end = beg + pd;
  float npad = (float)(pd - raw);
  const char* kvl = (const char*)kv + ll * 8;
  float a0 = 0.f, a1 = 0.f, a2 = 0.f, a3 = 0.f, den = 0.f;
  uint2 ka[4], va[4], kb2[4], vb2[4];
  int p = beg;
  loadKV(kvl, sp, p, half, ka, va);
  for (;;) {
    if (p + 8 < end) loadKV(kvl, sp, p + 8, half, kb2, vb2);
    computeKV(ka, va, qx, qy, a0, a1, a2, a3, den);
    p += 8;
    if (p >= end) break;
    if (p + 8 < end) loadKV(kvl, sp, p + 8, half, ka, va);
    computeKV(kb2, vb2, qx, qy, a0, a1, a2, a3, den);
    p += 8;
    if (p >= end) break;
  }
  den += __shfl_xor(den, 32);
  a0 += __shfl_xor(a0, 32);
  a1 += __shfl_xor(a1, 32);
  a2 += __shfl_xor(a2, 32);
  a3 += __shfl_xor(a3, 32);
  den -= npad;  // pads contributed exp(0)=1 each
  float inv = 1.0f / den;
  r0 = fmaf(a0, inv, r0);
  r1 = fmaf(a1, inv, r1);
  r2 = fmaf(a2, inv, r2);
  r3 = fmaf(a3, inv, r3);
}

__global__ __launch_bounds__(256) void fusedge_kernel(FuP P) {
  int gw = (blockIdx.x * 256 + threadIdx.x) >> 6;
  int l = threadIdx.x & 63;
  int ll = l & 31, half = l >> 5;
  if (gw < P.N0) {
    uint2 q = *(const uint2*)((const char*)P.qb0 + (size_t)gw * 256 + ll * 8);
    float r0 = 0.f, r1 = 0.f, r2 = 0.f, r3 = 0.f;
    fuse_rel(P.sp1, P.kv1, P.rs1, P.re1, gw, ll, half, q.x, q.y, r0, r1, r2, r3);
    fuse_rel(P.sp2, P.kv2, P.rs2, P.re2, gw, ll, half, q.x, q.y, r0, r1, r2, r3);
    if (half == 0) {
      uint2 o;
      o.x = f2h(r0 * 0.5f) | ((unsigned)f2h(r1 * 0.5f) << 16);
      o.y = f2h(r2 * 0.5f) | ((unsigned)f2h(r3 * 0.5f) << 16);
      *(uint2*)(P.Tb0 + (size_t)gw * 64 + 2 * ll) = o;
    }
  } else if (gw < P.N0 + P.N1) {
    int n = gw - P.N0;
    uint2 q = *(const uint2*)((const char*)P.qb1 + (size_t)n * 256 + ll * 8);
    float r0 = 0.f, r1 = 0.f, r2 = 0.f, r3 = 0.f;
    fuse_rel(P.sp0, P.kv0, P.rs0, P.re0, n, ll, half, q.x, q.y, r0, r1, r2, r3);
    if (half == 0) {
      uint2 o;
      o.x = f2h(r0) | ((unsigned)f2h(r1) << 16);
      o.y = f2h(r2) | ((unsigned)f2h(r3) << 16);
      *(uint2*)(P.Tb1 + (size_t)n * 64 + 2 * ll) = o;
    }
  }
}

// ---------- host ----------
extern "C" void kernel_launch(void* const* d_in, const int* in_sizes, int n_in,
                              void* d_out, int out_size, void* d_ws, size_t ws_size,
                              hipStream_t stream) {
  const float* h0 = (const float*)d_in[0];
  const float* h1 = (const float*)d_in[1];
  const int* srcs[3] = {(const int*)d_in[2], (const int*)d_in[4], (const int*)d_in[6]};
  const int* dsts[3] = {(const int*)d_in[3], (const int*)d_in[5], (const int*)d_in[7]};
  const float* Wk = (const float*)d_in[8];
  const float* bk = (const float*)d_in[9];
  const float* Wq = (const float*)d_in[10];
  const float* bq = (const float*)d_in[11];
  const float* Wv = (const float*)d_in[12];
  const float* bv = (const float*)d_in[13];
  const float* Wa = (const float*)d_in[14];
  const float* ba = (const float*)d_in[15];
  const float* rel_att = (const float*)d_in[16];
  const float* rel_msg = (const float*)d_in[17];
  const float* rel_pri = (const float*)d_in[18];
  const float* skip = (const float*)d_in[19];

  int N0 = in_sizes[0] / 128;
  int N1 = in_sizes[1] / 128;
  int E = in_sizes[2];
  int nsrc[3] = {N0, N1, N0};
  int ndst[3] = {N1, N0, N0};
  int maxN = N0 > N1 ? N0 : N1;

  char* base = (char*)d_ws;
  size_t off = 0;
  auto alloc = [&](size_t bytes) -> void* {
    void* p = base + off;
    off += (bytes + 255) & ~(size_t)255;
    return p;
  };

  unsigned short* qb0 = (unsigned short*)alloc((size_t)N0 * 128 * 2);
  unsigned short* qb1 = (unsigned short*)alloc((size_t)N1 * 128 * 2);
  unsigned short* kvb[3];  // interleaved [N+1][kr(128) | vr(128)] f16; last row = zeros
  for (int r = 0; r < 3; ++r) kvb[r] = (unsigned short*)alloc((size_t)(nsrc[r] + 1) * 256 * 2);
  unsigned short* Tb0 = (unsigned short*)alloc((size_t)N0 * 128 * 2);
  unsigned short* Tb1 = (unsigned short*)alloc((size_t)N1 * 128 * 2);
  unsigned short* Wkrb = (unsigned short*)alloc((size_t)3 * 16384 * 2);
  unsigned short* Wvrb = (unsigned short*)alloc((size_t)3 * 16384 * 2);
  unsigned short* Wqb = (unsigned short*)alloc((size_t)2 * 16384 * 2);
  unsigned short* Wab = (unsigned short*)alloc((size_t)2 * 16384 * 2);
  float* bkr = (float*)alloc(3 * 128 * 4);
  float* bvr = (float*)alloc(3 * 128 * 4);
  int* rp_s[3];
  int* rp_e[3];
  unsigned* spk[3];
  unsigned* bo[3];
  for (int r = 0; r < 3; ++r) {
    rp_s[r] = (int*)alloc((size_t)ndst[r] * 4);
    rp_e[r] = (int*)alloc((size_t)ndst[r] * 4);
    spk[r] = (unsigned*)alloc((size_t)NB * PSTRIDE * 4);
    bo[r] = (unsigned*)alloc((size_t)(E + 64) * 4);
  }
  int* bcnt = (int*)alloc((size_t)2 * 3 * NB * 4);  // bhist | bcur
  int* bhist = bcnt;
  int* bcur = bcnt + 3 * NB;
  (void)ws_size;

  // 0. clear counters
  hipMemsetAsync(bcnt, 0, (size_t)2 * 3 * NB * 4, stream);

  // 1. weight prep (+ zero pad-rows folded into cvt2)
  compose_w_kernel<<<dim3(3, 128, 2), 128, 0, stream>>>(Wk, bk, Wv, bv, rel_att, rel_msg,
                                                        rel_pri, Wkrb, bkr, Wvrb, bvr);
  cvt2_kernel<<<dim3(16, 3), 256, 0, stream>>>(Wq, Wqb, Wa, Wab, 4096,
                                               kvb[0] + (size_t)nsrc[0] * 256,
                                               kvb[1] + (size_t)nsrc[1] * 256,
                                               kvb[2] + (size_t)nsrc[2] * 256);

  // 2. combined proj GEMMs + bucket histogram (independent workloads, one launch)
  ProjFP pf;
  pf.A[0] = h0; pf.A[1] = h1;
  pf.M[0] = N0; pf.M[1] = N1;
  pf.nj[0] = 5; pf.nj[1] = 3;
  pf.W[0] = Wqb;            pf.b[0] = bq;        pf.out[0] = qb0;          pf.ostr[0] = 128;
  pf.W[1] = Wkrb;           pf.b[1] = bkr;       pf.out[1] = kvb[0];       pf.ostr[1] = 256;
  pf.W[2] = Wkrb + 32768;   pf.b[2] = bkr + 256; pf.out[2] = kvb[2];       pf.ostr[2] = 256;
  pf.W[3] = Wvrb;           pf.b[3] = bvr;       pf.out[3] = kvb[0] + 128; pf.ostr[3] = 256;
  pf.W[4] = Wvrb + 32768;   pf.b[4] = bvr + 256; pf.out[4] = kvb[2] + 128; pf.ostr[4] = 256;
  pf.W[5] = Wqb + 16384;    pf.b[5] = bq + 128;  pf.out[5] = qb1;          pf.ostr[5] = 128;
  pf.W[6] = Wkrb + 16384;   pf.b[6] = bkr + 128; pf.out[6] = kvb[1];       pf.ostr[6] = 256;
  pf.W[7] = Wvrb + 16384;   pf.b[7] = bvr + 128; pf.out[7] = kvb[1] + 128; pf.ostr[7] = 256;
  pf.W[8] = Wqb; pf.b[8] = bq; pf.out[8] = qb0; pf.ostr[8] = 128;  // unused
  pf.W[9] = Wqb; pf.b[9] = bq; pf.out[9] = qb0; pf.ostr[9] = 128;  // unused
  pf.dst[0] = dsts[0]; pf.dst[1] = dsts[1]; pf.dst[2] = dsts[2];
  pf.bh = bhist;
  pf.E = E;
  proj_bhist_kernel<<<dim3((maxN + 127) / 128, 5), 256, 0, stream>>>(pf);

  // 3. CSR: bin + padded per-bucket sort (each does its own bucket-total scan)
  bin_kernel<<<dim3((E + CHK - 1) / CHK, 3), 256, 0, stream>>>(
      srcs[0], dsts[0], srcs[1], dsts[1], srcs[2], dsts[2], bhist, bcur, bo[0], bo[1], bo[2], E);
  bsort_kernel<<<dim3(NB, 3), 256, 0, stream>>>(
      bo[0], bo[1], bo[2], bhist, rp_s[0], rp_s[1], rp_s[2], rp_e[0], rp_e[1], rp_e[2],
      spk[0], spk[1], spk[2], ndst[0], ndst[1], ndst[2], nsrc[0], nsrc[1], nsrc[2], E);

  // 4. fused edge pass (score + softmax + aggregate) -> f16 T
  FuP fp2;
  fp2.sp0 = spk[0]; fp2.sp1 = spk[1]; fp2.sp2 = spk[2];
  fp2.kv0 = (const unsigned*)kvb[0]; fp2.kv1 = (const unsigned*)kvb[1];
  fp2.kv2 = (const unsigned*)kvb[2];
  fp2.qb0 = (const unsigned*)qb0; fp2.qb1 = (const unsigned*)qb1;
  fp2.rs0 = rp_s[0]; fp2.rs1 = rp_s[1]; fp2.rs2 = rp_s[2];
  fp2.re0 = rp_e[0]; fp2.re1 = rp_e[1]; fp2.re2 = rp_e[2];
  fp2.Tb0 = (unsigned*)Tb0; fp2.Tb1 = (unsigned*)Tb1;
  fp2.N0 = N0; fp2.N1 = N1;
  int totw = N0 + N1;
  fusedge_kernel<<<(totw + 3) / 4, 256, 0, stream>>>(fp2);

  // 5. final GEMM + skip blend -> fp32 d_out
  final_gemm_mfma<<<dim3((maxN + 127) / 128, 2), 256, 0, stream>>>(
      (float*)d_out, Tb0, Tb1, Wab, ba, h0, h1, skip, N0, N1);
}